// Round 17
// baseline (118.580 us; speedup 1.0000x reference)
//
#include <hip/hip_runtime.h>
#include <hip/hip_bf16.h>

typedef __bf16 bf16;
typedef __bf16 bf16x8 __attribute__((ext_vector_type(8)));
typedef __bf16 bf16x4 __attribute__((ext_vector_type(4)));
typedef float  f32x4  __attribute__((ext_vector_type(4)));
typedef float  f32x16 __attribute__((ext_vector_type(16)));

#define MFMA16(A,B,C) __builtin_amdgcn_mfma_f32_16x16x32_bf16(A,B,C,0,0,0)
#define MFMA32(A,B,C) __builtin_amdgcn_mfma_f32_32x32x16_bf16(A,B,C,0,0,0)
#define EXP2(x) __builtin_amdgcn_exp2f(x)

static constexpr int SEQ = 2048;
static constexpr int NXC = 1024;
// Q pre-scale: 1/sqrt(64) * log2(e)  -> softmax runs in exp2 domain
#define QSCALE 0.1803368801111244f

static __device__ inline unsigned packb(float lo, float hi) {
  union { bf16 h[2]; unsigned u; } x;
  x.h[0] = (bf16)lo; x.h[1] = (bf16)hi;
  return x.u;
}
static __device__ inline bf16x8 frag_from_words(unsigned a, unsigned b,
                                                unsigned c, unsigned d) {
  union { unsigned u[4]; bf16x8 v; } x;
  x.u[0] = a; x.u[1] = b; x.u[2] = c; x.u[3] = d;
  return x.v;
}
__device__ __forceinline__ void gload16(const bf16* g, bf16* l) {
  __builtin_amdgcn_global_load_lds(
      (const __attribute__((address_space(1))) void*)g,
      (__attribute__((address_space(3))) void*)l, 16, 0, 0);
}

// ---- merged prep: f2b(x) + transpose-f2b(w_attn) + transpose-f2b(w_proj) ----
// grid sections: [0,4096) f2b x; [4096,4864) tr w_attn; [4864,5120) tr w_proj
__global__ __launch_bounds__(256) void prep_kernel(
    const float* __restrict__ x, const float* __restrict__ w_attn,
    const float* __restrict__ w_proj,
    bf16* __restrict__ xb, bf16* __restrict__ wabT, bf16* __restrict__ wpbT)
{
  __shared__ bf16 t[64][72];
  const int bid = blockIdx.x;
  const int tid = threadIdx.x;

  if (bid < 4096) {                       // ---- f2b of x ----
    int i = bid * 256 + tid;              // n4 = 1048576
    float4 v = ((const float4*)x)[i];
    bf16x4 o;
    o[0] = (bf16)v.x; o[1] = (bf16)v.y; o[2] = (bf16)v.z; o[3] = (bf16)v.w;
    ((bf16x4*)xb)[i] = o;
    return;
  }

  const float* in;
  bf16* out;
  int R, C, l;
  if (bid < 4864) { in = w_attn; out = wabT; R = 1024; C = 3072; l = bid - 4096;
                    }
  else            { in = w_proj; out = wpbT; R = 1024; C = 1024; l = bid - 4864; }
  const int nbx = C >> 6;
  const int c0 = (l % nbx) * 64, r0 = (l / nbx) * 64;

  const int lr = tid >> 4, lc = (tid & 15) * 4;
  #pragma unroll
  for (int p = 0; p < 4; ++p) {
    int rr = lr + p * 16;
    float4 v = *(const float4*)&in[(size_t)(r0 + rr) * C + c0 + lc];
    t[lc + 0][rr] = (bf16)v.x; t[lc + 1][rr] = (bf16)v.y;
    t[lc + 2][rr] = (bf16)v.z; t[lc + 3][rr] = (bf16)v.w;
  }
  __syncthreads();
  const int orow = tid >> 3, ocol = (tid & 7) * 8;
  #pragma unroll
  for (int p = 0; p < 2; ++p) {
    int rr = orow + p * 32;
    *(bf16x8*)&out[(size_t)(c0 + rr) * R + r0 + ocol] = *(const bf16x8*)&t[rr][ocol];
  }
}

// --- bf16 MFMA GEMM, 128x64 tile, BK=32, B^T input, global_load_lds,
//     double-buffered stage-ahead. 24 KB LDS -> 6 blocks/CU (convoy filling).
//     Verified structure (gemm2_bt rounds 15-16) + MODE-templated epilogue. ---
template<int MODE>
__global__ __launch_bounds__(256, 6) void gemm_nk(
    const bf16* __restrict__ A, const bf16* __restrict__ BT,
    const float* __restrict__ bias,
    bf16* __restrict__ qb, bf16* __restrict__ kb, bf16* __restrict__ vtb,
    float* __restrict__ outf, int K, int N, int nb)
{
  __shared__ bf16 As[2][128 * 32];
  __shared__ bf16 Bs[2][64 * 32];

  const int tid  = threadIdx.x;
  const int lane = tid & 63;
  const int w    = tid >> 6;
  // XCD-aware bijective swizzle (gridDim.x % 8 == 0)
  const int cpx  = gridDim.x >> 3;
  const int swzb = (blockIdx.x & 7) * cpx + (blockIdx.x >> 3);
  const int m0   = (swzb / nb) * 128;
  const int n0   = (swzb % nb) * 64;
  const int wrow = w * 32;
  const int g    = lane >> 4;
  const int c16  = lane & 15;

  f32x4 acc[2][4];
  #pragma unroll
  for (int i = 0; i < 2; ++i)
    #pragma unroll
    for (int j = 0; j < 4; ++j)
      acc[i][j] = f32x4{0.f, 0.f, 0.f, 0.f};

  // staging: lane stages phys row w*16 + (lane>>2), phys chunk lane&3.
  // source col pre-swizzled so phys chunk p of row r holds global chunk p^((r>>1)&3)
  const int srow = lane >> 2;
  const int scol = ((lane & 3) ^ ((lane >> 3) & 3)) * 8;
  const bf16* gA = A  + (size_t)(m0 + w * 16 + srow) * K + scol;
  const bf16* gB = BT + (size_t)(n0 + w * 16 + srow) * K + scol;   // rows 0..63
  const size_t rstep = (size_t)64 * K;
  const int rchunk = (g ^ ((c16 >> 1) & 3)) * 8;

  const int NT = K >> 5;

  auto STAGE = [&](int b, int k0) {
    bf16* lA = &As[b][w * 512];
    gload16(gA + k0,         lA);
    gload16(gA + k0 + rstep, lA + 64 * 32);
    gload16(gB + k0, &Bs[b][w * 512]);          // B: 64 rows, 1 op/wave
  };

  STAGE(0, 0);
  __syncthreads();

  int cur = 0;
  for (int t = 0; t < NT; ++t) {
    if (t + 1 < NT) STAGE(cur ^ 1, (t + 1) << 5);   // next tile in flight

    const bf16* pa = &As[cur][0];
    const bf16* pb = &Bs[cur][0];
    bf16x8 af[2], bfr[4];
    #pragma unroll
    for (int i = 0; i < 2; ++i)
      af[i] = *(const bf16x8*)&pa[(wrow + i * 16 + c16) * 32 + rchunk];
    #pragma unroll
    for (int j = 0; j < 4; ++j)
      bfr[j] = *(const bf16x8*)&pb[(j * 16 + c16) * 32 + rchunk];
    #pragma unroll
    for (int i = 0; i < 2; ++i)
      #pragma unroll
      for (int j = 0; j < 4; ++j)
        acc[i][j] = MFMA16(af[i], bfr[j], acc[i][j]);

    __syncthreads();   // drains stage (landed under compute) + read handoff
    cur ^= 1;
  }

  // epilogue. C layout: row = (lane>>4)*4 + r, col = lane&15
  #pragma unroll
  for (int i = 0; i < 2; ++i) {
    #pragma unroll
    for (int j = 0; j < 4; ++j) {
      #pragma unroll
      for (int r = 0; r < 4; ++r) {
        int gm = m0 + wrow + i * 16 + g * 4 + r;
        int gn = n0 + j * 16 + c16;
        float v = acc[i][j][r] + bias[gn];
        if (MODE == 0) {
          int which = gn >> 10;
          int cc = gn & 1023;
          int hh = cc >> 6, dd = cc & 63;
          int bb = gm >> 11, ss = gm & 2047;
          int bh = bb * 16 + hh;
          if (which == 0)
            qb[((size_t)bh * SEQ + ss) * 64 + dd] = (bf16)(v * QSCALE);
          else if (which == 1)
            kb[((size_t)bh * SEQ + ss) * 64 + dd] = (bf16)v;
          else
            vtb[((size_t)bh * 64 + dd) * SEQ + ss] = (bf16)v;
        } else {
          outf[(size_t)gm * N + gn] = v;
        }
      }
    }
  }
}

// ---- flash attention v10: LPT-balanced, PAIRED kv tiles (round-12 known-good) ----
__global__ __launch_bounds__(256, 2) void attn10_kernel(
    const bf16* __restrict__ q, const bf16* __restrict__ k,
    const bf16* __restrict__ vt, bf16* __restrict__ aout)
{
  __shared__ bf16 smem[4][8192];   // per slot: K [64][64] + V^T [64][64], swizzled

  const int tid  = threadIdx.x;
  const int lane = tid & 63;
  const int w    = tid >> 6;
  const int hi   = lane >> 5;
  const int q_l  = lane & 31;
  const int bid  = blockIdx.x;
  const int bh   = bid & 31;
  // LPT-balanced ordering: first 256 bids -> strips 15..8, next 256 -> 0..7
  const int idx8 = (bid & 255) >> 5;
  const int strip= (bid >> 8) ? idx8 : 15 - idx8;
  const int qr0  = strip * 128 + w * 32;     // this wave's first q row
  const int qg   = qr0 + q_l;
  const int nt   = 2 * strip + 2;            // kv tiles (even)
  const int nst2 = nt >> 1;                  // paired steps

  bf16x8 qf[4];
  {
    const bf16* qp = q + ((size_t)bh * SEQ + qr0 + q_l) * 64 + hi * 8;
    #pragma unroll
    for (int c = 0; c < 4; ++c) qf[c] = *(const bf16x8*)(qp + c * 16);
  }

  f32x16 Ot0 = (f32x16)0.f, Ot1 = (f32x16)0.f;
  float mrun = -INFINITY, lrun = 0.f;

  const int r1 = tid >> 3;
  const int c1 = (tid & 7) ^ (r1 & 7);
  const bf16* kB = k  + (size_t)bh * SEQ * 64;
  const bf16* vB = vt + (size_t)bh * 64 * SEQ;
  const int sw = q_l & 7;

  auto STAGE = [&](int b, int kv0) {
    bf16* buf = &smem[b][0];
    gload16(kB + (size_t)(kv0 + r1) * 64 + c1 * 8,       buf + w * 512);
    gload16(kB + (size_t)(kv0 + r1 + 32) * 64 + c1 * 8,  buf + 2048 + w * 512);
    gload16(vB + (size_t)r1 * SEQ + kv0 + c1 * 8,        buf + 4096 + w * 512);
    gload16(vB + (size_t)(r1 + 32) * SEQ + kv0 + c1 * 8, buf + 6144 + w * 512);
  };

  auto do_tile = [&](int b, int kv0) {
    const bf16* Kb = &smem[b][0];
    const bf16* Vb = &smem[b][4096];

    bf16x8 kf[8];
    #pragma unroll
    for (int c = 0; c < 4; ++c) {
      int ch = ((2 * c + hi) ^ sw) * 8;
      kf[c]     = *(const bf16x8*)&Kb[q_l * 64 + ch];
      kf[4 + c] = *(const bf16x8*)&Kb[(q_l + 32) * 64 + ch];
    }

    f32x16 st0 = (f32x16)0.f, st1 = (f32x16)0.f;
    __builtin_amdgcn_s_setprio(1);
    #pragma unroll
    for (int c = 0; c < 4; ++c) {
      st0 = MFMA32(kf[c],     qf[c], st0);
      st1 = MFMA32(kf[4 + c], qf[c], st1);
    }
    __builtin_amdgcn_s_setprio(0);

    bf16x8 vf[8];
    #pragma unroll
    for (int t2 = 0; t2 < 2; ++t2)
      #pragma unroll
      for (int h = 0; h < 2; ++h) {
        int ch = ((4 * t2 + 2 * h + hi) ^ sw) * 8;
        vf[t2 * 2 + h]     = *(const bf16x8*)&Vb[q_l * 64 + ch];
        vf[4 + t2 * 2 + h] = *(const bf16x8*)&Vb[(q_l + 32) * 64 + ch];
      }

    if (kv0 + 63 > qr0) {
      #pragma unroll
      for (int r = 0; r < 16; ++r) {
        int kvl = kv0 + (r & 3) + 8 * (r >> 2) + 4 * hi;
        if (kvl > qg)      st0[r] = -1e30f;
        if (kvl + 32 > qg) st1[r] = -1e30f;
      }
    }

    float m8[8];
    #pragma unroll
    for (int r = 0; r < 8; ++r)
      m8[r] = fmaxf(fmaxf(st0[r], st0[r + 8]), fmaxf(st1[r], st1[r + 8]));
    #pragma unroll
    for (int r = 0; r < 4; ++r) m8[r] = fmaxf(m8[r], m8[r + 4]);
    float pmax = fmaxf(fmaxf(m8[0], m8[1]), fmaxf(m8[2], m8[3]));

    float mnew;
    if (__all(pmax <= mrun + 8.f)) {
      mnew = mrun;                       // defer-max: P bounded by 2^8
    } else {
      float pm = fmaxf(pmax, __shfl_xor(pmax, 32));
      mnew = fmaxf(mrun, pm);
      const float sc = EXP2(mrun - mnew);
      lrun *= sc;
      Ot0 *= sc;
      Ot1 *= sc;
      mrun = mnew;
    }

    #pragma unroll
    for (int r = 0; r < 16; ++r) {
      st0[r] = EXP2(st0[r] - mnew);
      st1[r] = EXP2(st1[r] - mnew);
    }

    float s8[8];
    #pragma unroll
    for (int r = 0; r < 8; ++r)
      s8[r] = (st0[r] + st0[r + 8]) + (st1[r] + st1[r + 8]);
    #pragma unroll
    for (int r = 0; r < 4; ++r) s8[r] += s8[r + 4];
    lrun += (s8[0] + s8[1]) + (s8[2] + s8[3]);

    unsigned pw[16];
    #pragma unroll
    for (int m = 0; m < 8; ++m) {
      pw[m]     = packb(st0[2 * m], st0[2 * m + 1]);
      pw[8 + m] = packb(st1[2 * m], st1[2 * m + 1]);
    }
    __builtin_amdgcn_s_setprio(1);
    #pragma unroll
    for (int t2 = 0; t2 < 2; ++t2) {
      #pragma unroll
      for (int h = 0; h < 2; ++h) {
        auto sa = __builtin_amdgcn_permlane32_swap((int)pw[t2 * 8 + 4 * h + 0],
                                                   (int)pw[t2 * 8 + 4 * h + 2], false, false);
        auto sb = __builtin_amdgcn_permlane32_swap((int)pw[t2 * 8 + 4 * h + 1],
                                                   (int)pw[t2 * 8 + 4 * h + 3], false, false);
        bf16x8 pb = frag_from_words((unsigned)sa[0], (unsigned)sb[0],
                                    (unsigned)sa[1], (unsigned)sb[1]);
        Ot0 = MFMA32(vf[t2 * 2 + h],     pb, Ot0);
        Ot1 = MFMA32(vf[4 + t2 * 2 + h], pb, Ot1);
      }
    }
    __builtin_amdgcn_s_setprio(0);
  };

  // ---- paired pipeline: stage 2 tiles, compute 2 tiles, one drain+barrier ----
  STAGE(0, 0);
  STAGE(1, 64);
  asm volatile("s_waitcnt vmcnt(0)" ::: "memory");
  __builtin_amdgcn_s_barrier();

  int pair = 0;
  for (int s = 0; s < nst2; ++s) {
    if (s + 1 < nst2) {                        // next pair in flight
      STAGE(pair ^ 2,       (2 * s + 2) << 6);
      STAGE((pair ^ 2) + 1, (2 * s + 3) << 6);
    }
    if (((2 * s) << 6) <= qr0 + 31)     do_tile(pair,     (2 * s) << 6);
    if (((2 * s + 1) << 6) <= qr0 + 31) do_tile(pair + 1, (2 * s + 1) << 6);
    asm volatile("s_waitcnt vmcnt(0)" ::: "memory");
    __builtin_amdgcn_s_barrier();
    pair ^= 2;
  }

  lrun += __shfl_xor(lrun, 32);
  const float inv = 1.f / lrun;

  __syncthreads();
  bf16* ot = &smem[0][0];        // [128][72]
  const int orow = w * 32 + q_l;
  #pragma unroll
  for (int r = 0; r < 16; ++r) {
    int d = (r & 3) + 8 * (r >> 2) + 4 * hi;
    ot[orow * 72 + d]      = (bf16)(Ot0[r] * inv);
    ot[orow * 72 + d + 32] = (bf16)(Ot1[r] * inv);
  }
  __syncthreads();

  const int bb = bh >> 4, hh = bh & 15;
  const int qrow = w * 32 + (lane >> 1), half = lane & 1;
  const bf16* src = ot + qrow * 72 + half * 32;
  bf16* dst = aout + ((size_t)bb * SEQ + strip * 128 + qrow) * NXC + hh * 64 + half * 32;
  #pragma unroll
  for (int e = 0; e < 4; ++e)
    *(bf16x8*)(dst + e * 8) = *(const bf16x8*)(src + e * 8);
}

extern "C" void kernel_launch(void* const* d_in, const int* in_sizes, int n_in,
                              void* d_out, int out_size, void* d_ws, size_t ws_size,
                              hipStream_t stream) {
  const float* x      = (const float*)d_in[0];
  // d_in[1] = attention_mask — exactly causal, implemented structurally
  const float* w_attn = (const float*)d_in[2];
  const float* b_attn = (const float*)d_in[3];
  const float* w_proj = (const float*)d_in[4];
  const float* b_proj = (const float*)d_in[5];
  float* out = (float*)d_out;

  char* p = (char*)d_ws;
  bf16* xb   = (bf16*)p; p += (size_t)4194304 * 2;  // x bf16 [4096][1024]
  bf16* wabT = (bf16*)p; p += (size_t)3145728 * 2;  // w_attn^T bf16 [3072][1024]
  bf16* wpbT = (bf16*)p; p += (size_t)1048576 * 2;  // w_proj^T bf16 [1024][1024]
  bf16* qb   = (bf16*)p; p += (size_t)4194304 * 2;  // q [32][2048][64] (pre-scaled)
  bf16* kb   = (bf16*)p; p += (size_t)4194304 * 2;  // k [32][2048][64]
  bf16* vtb  = (bf16*)p; p += (size_t)4194304 * 2;  // v^T [32][64][2048]
  bf16* ab   = (bf16*)p; p += (size_t)4194304 * 2;  // attn out merged [4096][1024]

  prep_kernel<<<5120, 256, 0, stream>>>(x, w_attn, w_proj, xb, wabT, wpbT);

  // GEMM1: 128x64 tiles -> 1536 blocks = 6 blocks/CU (convoy filling)
  gemm_nk<0><<<1536, 256, 0, stream>>>(xb, wabT, b_attn, qb, kb, vtb,
                                       nullptr, 1024, 3072, 48);
  attn10_kernel<<<512, 256, 0, stream>>>(qb, kb, vtb, ab);
  // GEMM2: 128x64 tiles -> 512 blocks (round-15 known-good)
  gemm_nk<1><<<512, 256, 0, stream>>>(ab, wpbT, b_proj, nullptr, nullptr,
                                      nullptr, out, 1024, 1024, 16);
}

// Round 18
// 110.155 us; speedup vs baseline: 1.0765x; 1.0765x over previous
//
#include <hip/hip_runtime.h>
#include <hip/hip_bf16.h>

typedef __bf16 bf16;
typedef __bf16 bf16x8 __attribute__((ext_vector_type(8)));
typedef __bf16 bf16x4 __attribute__((ext_vector_type(4)));
typedef float  f32x4  __attribute__((ext_vector_type(4)));
typedef float  f32x16 __attribute__((ext_vector_type(16)));

#define MFMA16(A,B,C) __builtin_amdgcn_mfma_f32_16x16x32_bf16(A,B,C,0,0,0)
#define MFMA32(A,B,C) __builtin_amdgcn_mfma_f32_32x32x16_bf16(A,B,C,0,0,0)
#define EXP2(x) __builtin_amdgcn_exp2f(x)

static constexpr int SEQ = 2048;
static constexpr int NXC = 1024;
// Q pre-scale: 1/sqrt(64) * log2(e)  -> softmax runs in exp2 domain
#define QSCALE 0.1803368801111244f

static __device__ inline unsigned packb(float lo, float hi) {
  union { bf16 h[2]; unsigned u; } x;
  x.h[0] = (bf16)lo; x.h[1] = (bf16)hi;
  return x.u;
}
static __device__ inline bf16x8 frag_from_words(unsigned a, unsigned b,
                                                unsigned c, unsigned d) {
  union { unsigned u[4]; bf16x8 v; } x;
  x.u[0] = a; x.u[1] = b; x.u[2] = c; x.u[3] = d;
  return x.v;
}
__device__ __forceinline__ void gload16(const bf16* g, bf16* l) {
  __builtin_amdgcn_global_load_lds(
      (const __attribute__((address_space(1))) void*)g,
      (__attribute__((address_space(3))) void*)l, 16, 0, 0);
}

// ---- merged prep: f2b(x) + transpose-f2b(w_attn) + transpose-f2b(w_proj) ----
// grid sections: [0,4096) f2b x; [4096,4864) tr w_attn; [4864,5120) tr w_proj
__global__ __launch_bounds__(256) void prep_kernel(
    const float* __restrict__ x, const float* __restrict__ w_attn,
    const float* __restrict__ w_proj,
    bf16* __restrict__ xb, bf16* __restrict__ wabT, bf16* __restrict__ wpbT)
{
  __shared__ bf16 t[64][72];
  const int bid = blockIdx.x;
  const int tid = threadIdx.x;

  if (bid < 4096) {                       // ---- f2b of x ----
    int i = bid * 256 + tid;              // n4 = 1048576
    float4 v = ((const float4*)x)[i];
    bf16x4 o;
    o[0] = (bf16)v.x; o[1] = (bf16)v.y; o[2] = (bf16)v.z; o[3] = (bf16)v.w;
    ((bf16x4*)xb)[i] = o;
    return;
  }

  const float* in;
  bf16* out;
  int R, C, l;
  if (bid < 4864) { in = w_attn; out = wabT; R = 1024; C = 3072; l = bid - 4096;
                    }
  else            { in = w_proj; out = wpbT; R = 1024; C = 1024; l = bid - 4864; }
  const int nbx = C >> 6;
  const int c0 = (l % nbx) * 64, r0 = (l / nbx) * 64;

  const int lr = tid >> 4, lc = (tid & 15) * 4;
  #pragma unroll
  for (int p = 0; p < 4; ++p) {
    int rr = lr + p * 16;
    float4 v = *(const float4*)&in[(size_t)(r0 + rr) * C + c0 + lc];
    t[lc + 0][rr] = (bf16)v.x; t[lc + 1][rr] = (bf16)v.y;
    t[lc + 2][rr] = (bf16)v.z; t[lc + 3][rr] = (bf16)v.w;
  }
  __syncthreads();
  const int orow = tid >> 3, ocol = (tid & 7) * 8;
  #pragma unroll
  for (int p = 0; p < 2; ++p) {
    int rr = orow + p * 32;
    *(bf16x8*)&out[(size_t)(c0 + rr) * R + r0 + ocol] = *(const bf16x8*)&t[rr][ocol];
  }
}

// --- bf16 MFMA GEMM, 128x128 tile, BK=32, B^T input, global_load_lds,
//     double-buffered stage-ahead + linear XCD swizzle (round-12 known-good) ---
template<int MODE>
__global__ __launch_bounds__(256, 3) void gemm_bt(
    const bf16* __restrict__ A, const bf16* __restrict__ BT,
    const float* __restrict__ bias,
    bf16* __restrict__ qb, bf16* __restrict__ kb, bf16* __restrict__ vtb,
    float* __restrict__ outf, int K, int N, int nb)
{
  __shared__ bf16 As[2][128 * 32];
  __shared__ bf16 Bs[2][128 * 32];

  const int tid  = threadIdx.x;
  const int lane = tid & 63;
  const int w    = tid >> 6;
  // XCD-aware bijective swizzle (gridDim.x % 8 == 0)
  const int cpx  = gridDim.x >> 3;
  const int swzb = (blockIdx.x & 7) * cpx + (blockIdx.x >> 3);
  const int m0   = (swzb / nb) * 128;
  const int n0   = (swzb % nb) * 128;
  const int wrow = (w >> 1) * 64;
  const int wcol = (w & 1) * 64;
  const int g    = lane >> 4;
  const int c16  = lane & 15;

  f32x4 acc[4][4];
  #pragma unroll
  for (int i = 0; i < 4; ++i)
    #pragma unroll
    for (int j = 0; j < 4; ++j)
      acc[i][j] = f32x4{0.f, 0.f, 0.f, 0.f};

  // staging: lane stages phys row w*16 + (lane>>2) (+64), phys chunk lane&3.
  // source col pre-swizzled so phys chunk p of row r holds global chunk p^((r>>1)&3)
  const int srow = lane >> 2;
  const int scol = ((lane & 3) ^ ((lane >> 3) & 3)) * 8;
  const bf16* gA = A  + (size_t)(m0 + w * 16 + srow) * K + scol;
  const bf16* gB = BT + (size_t)(n0 + w * 16 + srow) * K + scol;
  const size_t rstep = (size_t)64 * K;
  const int rchunk = (g ^ ((c16 >> 1) & 3)) * 8;

  const int NT = K >> 5;

  auto STAGE = [&](int b, int k0) {
    bf16* lA = &As[b][w * 512];
    bf16* lB = &Bs[b][w * 512];
    gload16(gA + k0,         lA);
    gload16(gA + k0 + rstep, lA + 64 * 32);
    gload16(gB + k0,         lB);
    gload16(gB + k0 + rstep, lB + 64 * 32);
  };

  STAGE(0, 0);
  __syncthreads();

  int cur = 0;
  for (int t = 0; t < NT; ++t) {
    if (t + 1 < NT) STAGE(cur ^ 1, (t + 1) << 5);   // next tile in flight

    const bf16* pa = &As[cur][0];
    const bf16* pb = &Bs[cur][0];
    bf16x8 af[4], bfr[4];
    #pragma unroll
    for (int i = 0; i < 4; ++i)
      af[i] = *(const bf16x8*)&pa[(wrow + i * 16 + c16) * 32 + rchunk];
    #pragma unroll
    for (int j = 0; j < 4; ++j)
      bfr[j] = *(const bf16x8*)&pb[(wcol + j * 16 + c16) * 32 + rchunk];
    #pragma unroll
    for (int i = 0; i < 4; ++i)
      #pragma unroll
      for (int j = 0; j < 4; ++j)
        acc[i][j] = MFMA16(af[i], bfr[j], acc[i][j]);

    __syncthreads();   // drains stage (landed under compute) + read handoff
    cur ^= 1;
  }

  // epilogue. C layout: row = (lane>>4)*4 + r, col = lane&15
  #pragma unroll
  for (int i = 0; i < 4; ++i) {
    #pragma unroll
    for (int j = 0; j < 4; ++j) {
      #pragma unroll
      for (int r = 0; r < 4; ++r) {
        int gm = m0 + wrow + i * 16 + g * 4 + r;
        int gn = n0 + wcol + j * 16 + c16;
        float v = acc[i][j][r] + bias[gn];
        if (MODE == 0) {
          int which = gn >> 10;
          int cc = gn & 1023;
          int hh = cc >> 6, dd = cc & 63;
          int bb = gm >> 11, ss = gm & 2047;
          int bh = bb * 16 + hh;
          if (which == 0)
            qb[((size_t)bh * SEQ + ss) * 64 + dd] = (bf16)(v * QSCALE);
          else if (which == 1)
            kb[((size_t)bh * SEQ + ss) * 64 + dd] = (bf16)v;
          else
            vtb[((size_t)bh * 64 + dd) * SEQ + ss] = (bf16)v;
        } else {
          outf[(size_t)gm * N + gn] = v;
        }
      }
    }
  }
}

// --- GEMM2: 128x64 tile, BK=32 -> 512 blocks = 2 blocks/CU (convoy filling) ---
// Same staging/swizzle math as gemm_bt; wave w owns rows [w*32, w*32+32).
__global__ __launch_bounds__(256, 3) void gemm2_bt(
    const bf16* __restrict__ A, const bf16* __restrict__ BT,
    const float* __restrict__ bias, float* __restrict__ outf, int K, int N)
{
  __shared__ bf16 As[2][128 * 32];
  __shared__ bf16 Bs[2][64 * 32];

  const int tid  = threadIdx.x;
  const int lane = tid & 63;
  const int w    = tid >> 6;
  const int cpx  = gridDim.x >> 3;
  const int swzb = (blockIdx.x & 7) * cpx + (blockIdx.x >> 3);
  const int nb   = N >> 6;                    // 64-wide n tiles
  const int m0   = (swzb / nb) * 128;
  const int n0   = (swzb % nb) * 64;
  const int wrow = w * 32;
  const int g    = lane >> 4;
  const int c16  = lane & 15;

  f32x4 acc[2][4];
  #pragma unroll
  for (int i = 0; i < 2; ++i)
    #pragma unroll
    for (int j = 0; j < 4; ++j)
      acc[i][j] = f32x4{0.f, 0.f, 0.f, 0.f};

  const int srow = lane >> 2;
  const int scol = ((lane & 3) ^ ((lane >> 3) & 3)) * 8;
  const bf16* gA = A  + (size_t)(m0 + w * 16 + srow) * K + scol;
  const bf16* gB = BT + (size_t)(n0 + w * 16 + srow) * K + scol;   // rows 0..63
  const size_t rstep = (size_t)64 * K;
  const int rchunk = (g ^ ((c16 >> 1) & 3)) * 8;

  const int NT = K >> 5;

  auto STAGE = [&](int b, int k0) {
    bf16* lA = &As[b][w * 512];
    gload16(gA + k0,         lA);
    gload16(gA + k0 + rstep, lA + 64 * 32);
    gload16(gB + k0, &Bs[b][w * 512]);          // B: 64 rows, 1 op/wave
  };

  STAGE(0, 0);
  __syncthreads();

  int cur = 0;
  for (int t = 0; t < NT; ++t) {
    if (t + 1 < NT) STAGE(cur ^ 1, (t + 1) << 5);

    const bf16* pa = &As[cur][0];
    const bf16* pb = &Bs[cur][0];
    bf16x8 af[2], bfr[4];
    #pragma unroll
    for (int i = 0; i < 2; ++i)
      af[i] = *(const bf16x8*)&pa[(wrow + i * 16 + c16) * 32 + rchunk];
    #pragma unroll
    for (int j = 0; j < 4; ++j)
      bfr[j] = *(const bf16x8*)&pb[(j * 16 + c16) * 32 + rchunk];
    #pragma unroll
    for (int i = 0; i < 2; ++i)
      #pragma unroll
      for (int j = 0; j < 4; ++j)
        acc[i][j] = MFMA16(af[i], bfr[j], acc[i][j]);

    __syncthreads();
    cur ^= 1;
  }

  #pragma unroll
  for (int i = 0; i < 2; ++i) {
    #pragma unroll
    for (int j = 0; j < 4; ++j) {
      #pragma unroll
      for (int r = 0; r < 4; ++r) {
        int gm = m0 + wrow + i * 16 + g * 4 + r;
        int gn = n0 + j * 16 + c16;
        outf[(size_t)gm * N + gn] = acc[i][j][r] + bias[gn];
      }
    }
  }
}

// ---- flash attention v10: LPT-balanced, PAIRED kv tiles (round-12 known-good) ----
__global__ __launch_bounds__(256, 2) void attn10_kernel(
    const bf16* __restrict__ q, const bf16* __restrict__ k,
    const bf16* __restrict__ vt, bf16* __restrict__ aout)
{
  __shared__ bf16 smem[4][8192];   // per slot: K [64][64] + V^T [64][64], swizzled

  const int tid  = threadIdx.x;
  const int lane = tid & 63;
  const int w    = tid >> 6;
  const int hi   = lane >> 5;
  const int q_l  = lane & 31;
  const int bid  = blockIdx.x;
  const int bh   = bid & 31;
  // LPT-balanced ordering: first 256 bids -> strips 15..8, next 256 -> 0..7
  const int idx8 = (bid & 255) >> 5;
  const int strip= (bid >> 8) ? idx8 : 15 - idx8;
  const int qr0  = strip * 128 + w * 32;     // this wave's first q row
  const int qg   = qr0 + q_l;
  const int nt   = 2 * strip + 2;            // kv tiles (even)
  const int nst2 = nt >> 1;                  // paired steps

  bf16x8 qf[4];
  {
    const bf16* qp = q + ((size_t)bh * SEQ + qr0 + q_l) * 64 + hi * 8;
    #pragma unroll
    for (int c = 0; c < 4; ++c) qf[c] = *(const bf16x8*)(qp + c * 16);
  }

  f32x16 Ot0 = (f32x16)0.f, Ot1 = (f32x16)0.f;
  float mrun = -INFINITY, lrun = 0.f;

  const int r1 = tid >> 3;
  const int c1 = (tid & 7) ^ (r1 & 7);
  const bf16* kB = k  + (size_t)bh * SEQ * 64;
  const bf16* vB = vt + (size_t)bh * 64 * SEQ;
  const int sw = q_l & 7;

  auto STAGE = [&](int b, int kv0) {
    bf16* buf = &smem[b][0];
    gload16(kB + (size_t)(kv0 + r1) * 64 + c1 * 8,       buf + w * 512);
    gload16(kB + (size_t)(kv0 + r1 + 32) * 64 + c1 * 8,  buf + 2048 + w * 512);
    gload16(vB + (size_t)r1 * SEQ + kv0 + c1 * 8,        buf + 4096 + w * 512);
    gload16(vB + (size_t)(r1 + 32) * SEQ + kv0 + c1 * 8, buf + 6144 + w * 512);
  };

  auto do_tile = [&](int b, int kv0) {
    const bf16* Kb = &smem[b][0];
    const bf16* Vb = &smem[b][4096];

    bf16x8 kf[8];
    #pragma unroll
    for (int c = 0; c < 4; ++c) {
      int ch = ((2 * c + hi) ^ sw) * 8;
      kf[c]     = *(const bf16x8*)&Kb[q_l * 64 + ch];
      kf[4 + c] = *(const bf16x8*)&Kb[(q_l + 32) * 64 + ch];
    }

    f32x16 st0 = (f32x16)0.f, st1 = (f32x16)0.f;
    __builtin_amdgcn_s_setprio(1);
    #pragma unroll
    for (int c = 0; c < 4; ++c) {
      st0 = MFMA32(kf[c],     qf[c], st0);
      st1 = MFMA32(kf[4 + c], qf[c], st1);
    }
    __builtin_amdgcn_s_setprio(0);

    bf16x8 vf[8];
    #pragma unroll
    for (int t2 = 0; t2 < 2; ++t2)
      #pragma unroll
      for (int h = 0; h < 2; ++h) {
        int ch = ((4 * t2 + 2 * h + hi) ^ sw) * 8;
        vf[t2 * 2 + h]     = *(const bf16x8*)&Vb[q_l * 64 + ch];
        vf[4 + t2 * 2 + h] = *(const bf16x8*)&Vb[(q_l + 32) * 64 + ch];
      }

    if (kv0 + 63 > qr0) {
      #pragma unroll
      for (int r = 0; r < 16; ++r) {
        int kvl = kv0 + (r & 3) + 8 * (r >> 2) + 4 * hi;
        if (kvl > qg)      st0[r] = -1e30f;
        if (kvl + 32 > qg) st1[r] = -1e30f;
      }
    }

    float m8[8];
    #pragma unroll
    for (int r = 0; r < 8; ++r)
      m8[r] = fmaxf(fmaxf(st0[r], st0[r + 8]), fmaxf(st1[r], st1[r + 8]));
    #pragma unroll
    for (int r = 0; r < 4; ++r) m8[r] = fmaxf(m8[r], m8[r + 4]);
    float pmax = fmaxf(fmaxf(m8[0], m8[1]), fmaxf(m8[2], m8[3]));

    float mnew;
    if (__all(pmax <= mrun + 8.f)) {
      mnew = mrun;                       // defer-max: P bounded by 2^8
    } else {
      float pm = fmaxf(pmax, __shfl_xor(pmax, 32));
      mnew = fmaxf(mrun, pm);
      const float sc = EXP2(mrun - mnew);
      lrun *= sc;
      Ot0 *= sc;
      Ot1 *= sc;
      mrun = mnew;
    }

    #pragma unroll
    for (int r = 0; r < 16; ++r) {
      st0[r] = EXP2(st0[r] - mnew);
      st1[r] = EXP2(st1[r] - mnew);
    }

    float s8[8];
    #pragma unroll
    for (int r = 0; r < 8; ++r)
      s8[r] = (st0[r] + st0[r + 8]) + (st1[r] + st1[r + 8]);
    #pragma unroll
    for (int r = 0; r < 4; ++r) s8[r] += s8[r + 4];
    lrun += (s8[0] + s8[1]) + (s8[2] + s8[3]);

    unsigned pw[16];
    #pragma unroll
    for (int m = 0; m < 8; ++m) {
      pw[m]     = packb(st0[2 * m], st0[2 * m + 1]);
      pw[8 + m] = packb(st1[2 * m], st1[2 * m + 1]);
    }
    __builtin_amdgcn_s_setprio(1);
    #pragma unroll
    for (int t2 = 0; t2 < 2; ++t2) {
      #pragma unroll
      for (int h = 0; h < 2; ++h) {
        auto sa = __builtin_amdgcn_permlane32_swap((int)pw[t2 * 8 + 4 * h + 0],
                                                   (int)pw[t2 * 8 + 4 * h + 2], false, false);
        auto sb = __builtin_amdgcn_permlane32_swap((int)pw[t2 * 8 + 4 * h + 1],
                                                   (int)pw[t2 * 8 + 4 * h + 3], false, false);
        bf16x8 pb = frag_from_words((unsigned)sa[0], (unsigned)sb[0],
                                    (unsigned)sa[1], (unsigned)sb[1]);
        Ot0 = MFMA32(vf[t2 * 2 + h],     pb, Ot0);
        Ot1 = MFMA32(vf[4 + t2 * 2 + h], pb, Ot1);
      }
    }
    __builtin_amdgcn_s_setprio(0);
  };

  // ---- paired pipeline: stage 2 tiles, compute 2 tiles, one drain+barrier ----
  STAGE(0, 0);
  STAGE(1, 64);
  asm volatile("s_waitcnt vmcnt(0)" ::: "memory");
  __builtin_amdgcn_s_barrier();

  int pair = 0;
  for (int s = 0; s < nst2; ++s) {
    if (s + 1 < nst2) {                        // next pair in flight
      STAGE(pair ^ 2,       (2 * s + 2) << 6);
      STAGE((pair ^ 2) + 1, (2 * s + 3) << 6);
    }
    if (((2 * s) << 6) <= qr0 + 31)     do_tile(pair,     (2 * s) << 6);
    if (((2 * s + 1) << 6) <= qr0 + 31) do_tile(pair + 1, (2 * s + 1) << 6);
    asm volatile("s_waitcnt vmcnt(0)" ::: "memory");
    __builtin_amdgcn_s_barrier();
    pair ^= 2;
  }

  lrun += __shfl_xor(lrun, 32);
  const float inv = 1.f / lrun;

  __syncthreads();
  bf16* ot = &smem[0][0];        // [128][72]
  const int orow = w * 32 + q_l;
  #pragma unroll
  for (int r = 0; r < 16; ++r) {
    int d = (r & 3) + 8 * (r >> 2) + 4 * hi;
    ot[orow * 72 + d]      = (bf16)(Ot0[r] * inv);
    ot[orow * 72 + d + 32] = (bf16)(Ot1[r] * inv);
  }
  __syncthreads();

  const int bb = bh >> 4, hh = bh & 15;
  const int qrow = w * 32 + (lane >> 1), half = lane & 1;
  const bf16* src = ot + qrow * 72 + half * 32;
  bf16* dst = aout + ((size_t)bb * SEQ + strip * 128 + qrow) * NXC + hh * 64 + half * 32;
  #pragma unroll
  for (int e = 0; e < 4; ++e)
    *(bf16x8*)(dst + e * 8) = *(const bf16x8*)(src + e * 8);
}

extern "C" void kernel_launch(void* const* d_in, const int* in_sizes, int n_in,
                              void* d_out, int out_size, void* d_ws, size_t ws_size,
                              hipStream_t stream) {
  const float* x      = (const float*)d_in[0];
  // d_in[1] = attention_mask — exactly causal, implemented structurally
  const float* w_attn = (const float*)d_in[2];
  const float* b_attn = (const float*)d_in[3];
  const float* w_proj = (const float*)d_in[4];
  const float* b_proj = (const float*)d_in[5];
  float* out = (float*)d_out;

  char* p = (char*)d_ws;
  bf16* xb   = (bf16*)p; p += (size_t)4194304 * 2;  // x bf16 [4096][1024]
  bf16* wabT = (bf16*)p; p += (size_t)3145728 * 2;  // w_attn^T bf16 [3072][1024]
  bf16* wpbT = (bf16*)p; p += (size_t)1048576 * 2;  // w_proj^T bf16 [1024][1024]
  bf16* qb   = (bf16*)p; p += (size_t)4194304 * 2;  // q [32][2048][64] (pre-scaled)
  bf16* kb   = (bf16*)p; p += (size_t)4194304 * 2;  // k [32][2048][64]
  bf16* vtb  = (bf16*)p; p += (size_t)4194304 * 2;  // v^T [32][64][2048]
  bf16* ab   = (bf16*)p; p += (size_t)4194304 * 2;  // attn out merged [4096][1024]

  prep_kernel<<<5120, 256, 0, stream>>>(x, w_attn, w_proj, xb, wabT, wpbT);

  gemm_bt<0><<<768, 256, 0, stream>>>(xb, wabT, b_attn, qb, kb, vtb,
                                      nullptr, 1024, 3072, 24);
  attn10_kernel<<<512, 256, 0, stream>>>(qb, kb, vtb, ab);
  gemm2_bt<<<512, 256, 0, stream>>>(ab, wpbT, b_proj, out, 1024, 1024);
}